// Round 2
// baseline (398.466 us; speedup 1.0000x reference)
//
#include <hip/hip_runtime.h>

typedef __bf16 bf16x8 __attribute__((ext_vector_type(8)));
typedef __bf16 bf16x4 __attribute__((ext_vector_type(4)));
typedef float  f32x4  __attribute__((ext_vector_type(4)));
typedef int    v4i    __attribute__((ext_vector_type(4)));

#define LOG2E 1.4426950408889634f

__device__ __forceinline__ float fexp(float x){ return __builtin_amdgcn_exp2f(x * LOG2E); }
__device__ __forceinline__ float sigm(float x){ return __builtin_amdgcn_rcpf(1.0f + fexp(-x)); }
__device__ __forceinline__ float ftanh(float x){
  float r = __builtin_amdgcn_rcpf(1.0f + __builtin_amdgcn_exp2f(-2.0f*LOG2E*x));
  return 2.0f*r - 1.0f;
}
__device__ __forceinline__ f32x4 MFMA(bf16x8 a, bf16x8 b, f32x4 c){
  return __builtin_amdgcn_mfma_f32_16x16x32_bf16(a, b, c, 0, 0, 0);
}
#define BC(w) __builtin_bit_cast(v4i, (w))

/* Register budget: AGPR = 30 awf + 2 kt6-o frags = 128.  VGPR: acc 24 + t 24
   + wvf(10) 40 + A7/Ax 8 + cst/igv/pv 12 + misc ~=126.  2 waves/SIMD. */
#define GRP_A(LEAD, A_, KT_) asm volatile(LEAD                  \
    "v_mfma_f32_16x16x32_bf16 %0, %6, %7, %0\n\t"               \
    "v_mfma_f32_16x16x32_bf16 %1, %6, %8, %1\n\t"               \
    "v_mfma_f32_16x16x32_bf16 %2, %6, %9, %2\n\t"               \
    "v_mfma_f32_16x16x32_bf16 %3, %6, %10, %3\n\t"              \
    "v_mfma_f32_16x16x32_bf16 %4, %6, %11, %4\n\t"              \
    "v_mfma_f32_16x16x32_bf16 %5, %6, %12, %5\n\t"              \
    "s_nop 3"                                                   \
    : "+v"(acc0),"+v"(acc1),"+v"(acc2),"+v"(acc3),"+v"(acc4),"+v"(acc5) \
    : "v"(A_), "a"(awf[(KT_)]),"a"(awf[(KT_)+5]),"a"(awf[(KT_)+10]),    \
      "a"(awf[(KT_)+15]),"a"(awf[(KT_)+20]),"a"(awf[(KT_)+25]))

#define GRP_V(A_, O_) asm volatile(                             \
    "v_mfma_f32_16x16x32_bf16 %0, %6, %7, %0\n\t"               \
    "v_mfma_f32_16x16x32_bf16 %1, %6, %8, %1\n\t"               \
    "v_mfma_f32_16x16x32_bf16 %2, %6, %9, %2\n\t"               \
    "v_mfma_f32_16x16x32_bf16 %3, %6, %10, %3\n\t"              \
    "v_mfma_f32_16x16x32_bf16 %4, %6, %11, %4\n\t"              \
    "v_mfma_f32_16x16x32_bf16 %5, %6, %12, %5\n\t"              \
    "s_nop 3"                                                   \
    : "+v"(acc0),"+v"(acc1),"+v"(acc2),"+v"(acc3),"+v"(acc4),"+v"(acc5) \
    : "v"(A_), "v"(wvf[(O_)]),"v"(wvf[(O_)+2]),"v"(wvf[(O_)+4]),        \
      "v"(wvf[(O_)+6]),"v"(wvf[(O_)+8]),"v"(wvf[(O_)+10]))

/* kt6 group: f/g gate frags in VGPR, o gate frags in AGPR (budget) */
#define GRP_V6(A_) asm volatile(                                \
    "v_mfma_f32_16x16x32_bf16 %0, %6, %7, %0\n\t"               \
    "v_mfma_f32_16x16x32_bf16 %1, %6, %8, %1\n\t"               \
    "v_mfma_f32_16x16x32_bf16 %2, %6, %9, %2\n\t"               \
    "v_mfma_f32_16x16x32_bf16 %3, %6, %10, %3\n\t"              \
    "v_mfma_f32_16x16x32_bf16 %4, %6, %11, %4\n\t"              \
    "v_mfma_f32_16x16x32_bf16 %5, %6, %12, %5\n\t"              \
    "s_nop 3"                                                   \
    : "+v"(acc0),"+v"(acc1),"+v"(acc2),"+v"(acc3),"+v"(acc4),"+v"(acc5) \
    : "v"(A_), "v"(wvf[1]),"v"(wvf[3]),"v"(wvf[5]),"v"(wvf[7]),         \
      "a"(aw6o0),"a"(aw6o1))

/* Raw workgroup barrier: drain LDS but NOT vmcnt (keeps x prefetch in flight). */
#define BARRIER() asm volatile("s_waitcnt lgkmcnt(0)\n\ts_barrier" ::: "memory")

// B=2048, T=128, D=32, H=256, S=39, PM=12
// 256 wg x 512 threads (8 waves), 8 batch rows per wg (tile rows 8-15 zero).
__global__ void
__attribute__((amdgpu_flat_work_group_size(512,512), amdgpu_waves_per_eu(2,2)))
ealstm_kernel(
    const float* __restrict__ x,      const float* __restrict__ latlons,
    const float* __restrict__ yearly, const float* __restrict__ pm,
    const float* __restrict__ Wf_i, const float* __restrict__ Wf_h, const float* __restrict__ bf_h,
    const float* __restrict__ Wu,   const float* __restrict__ bu,
    const float* __restrict__ Wg_i, const float* __restrict__ Wg_h, const float* __restrict__ bg_h,
    const float* __restrict__ Wo_i, const float* __restrict__ Wo_h, const float* __restrict__ bo_h,
    const float* __restrict__ Wd0,  const float* __restrict__ bd0,
    const float* __restrict__ Wd1,  const float* __restrict__ bd1,
    float* __restrict__ out)
{
  __shared__ __align__(16) __bf16 hbuf[2][4096];
  __shared__ __align__(16) __bf16 xbuf[2][16*40];
  __shared__ __align__(16) __bf16 wlds[2*48*512];
  __shared__ __align__(16) float  xs[16*64];

  const int tid  = threadIdx.x;
  const int w    = tid >> 6;
  const int lane = tid & 63;
  const int q    = lane >> 4;
  const int l    = lane & 15;
  const int wgb  = blockIdx.x * 8;

  const float* Wh[3] = {Wf_h, Wg_h, Wo_h};
  const float* Wi[3] = {Wf_i, Wg_i, Wo_i};

  /* ---------------- init: LDS fills ---------------- */
  for(int idx = tid; idx < 16*64; idx += 512){
    int m = idx >> 6, k = idx & 63;
    float v = 0.0f;
    if(m < 8){
      int b = wgb + m;
      if(k < 2) v = latlons[b*2 + k];
      else if(k < 39) v = yearly[b*37 + (k-2)];
    }
    xs[idx] = v;
  }
  for(int idx = tid; idx < 2*4096; idx += 512) ((__bf16*)hbuf)[idx] = (__bf16)0.0f;
  {
    int buf = tid >> 8, r = 8 + ((tid >> 5) & 7), c = tid & 31;
    xbuf[buf][r*40 + c] = (__bf16)0.0f;
  }
  if(tid < 256){
    int m = tid >> 5, k = tid & 31;
    xbuf[0][m*40 + k] = (__bf16)x[(size_t)(wgb + m)*4096 + k];
  }
  for(int grp = tid; grp < 2*48*64; grp += 512){
    int frag = grp >> 6, ln = grp & 63;
    int kk = frag / 48, f2 = frag % 48;
    int g = f2 >> 4, nt = f2 & 15;
    int q2 = ln >> 4, l2 = ln & 15;
    int cc = nt*16 + l2;
    const float* p = (kk == 0) ? (Wh[g] + cc*256 + 224 + q2*8)
                               : (Wi[g] + cc*32  + q2*8);
    bf16x8 v;
    #pragma unroll
    for(int j=0;j<8;j++) v[j] = (__bf16)p[j];
    *(bf16x8*)&wlds[frag*512 + ln*8] = v;
  }

  const int  srcl = lane & 31;
  const bool lo   = lane < 32;
  const int  qq4  = (q & 1) * 4;
  const int  colw = w*32 + ((lane & 32) >> 1) + l;
  const int  hwb  = (colw >> 5)*512 + qq4*32 + ((colw >> 3) & 3)*8 + (colw & 7);
  const unsigned waddr0 = (unsigned)(unsigned long long)&wlds[(0*48 + w*2)*512 + lane*8];
  const unsigned waddr1 = waddr0 + 49152u;
  const unsigned hA0 = (unsigned)(unsigned long long)&hbuf[0][l*32 + q*8];
  const unsigned xA0 = (unsigned)(unsigned long long)&xbuf[0][l*40 + q*8];
  const float b3f = bf_h[colw], b3g = bg_h[colw], b3o = bo_h[colw];

  __syncthreads();

  /* ---------------- i_gate = sigmoid(x_s @ Wu^T + bu) ---------------- */
  f32x4 igv;
  {
    float bu0 = bu[w*32 + l], bu1 = bu[w*32 + 16 + l];
    f32x4 iga0 = {bu0,bu0,bu0,bu0};
    f32x4 iga1 = {bu1,bu1,bu1,bu1};
    #pragma unroll
    for(int kt=0; kt<2; kt++){
      bf16x8 a;
      const float* xr = &xs[l*64 + kt*32 + q*8];
      #pragma unroll
      for(int j=0;j<8;j++) a[j] = (__bf16)xr[j];
      #pragma unroll
      for(int n=0;n<2;n++){
        int cc = w*32 + n*16 + l;
        bf16x8 b;
        #pragma unroll
        for(int j=0;j<8;j++){
          int k = kt*32 + q*8 + j;
          b[j] = (__bf16)((k < 39) ? Wu[cc*39 + k] : 0.0f);
        }
        if(n == 0) iga0 = MFMA(a, b, iga0); else iga1 = MFMA(a, b, iga1);
      }
    }
    #pragma unroll
    for(int i=0;i<4;i++){
      float s0 = sigm(iga0[i]);
      float s1 = __shfl(sigm(iga1[i]), srcl);
      igv[i] = lo ? s0 : s1;
    }
  }

  /* ---------------- weight frags: wvf (VGPR, kt5/6 minus o-kt6) ---------- */
  v4i wvf[12];
  v4i aw6o0, aw6o1;
  #pragma unroll
  for(int f = 0; f < 12; f++){
    int gn = f >> 1, kt = 5 + (f & 1);
    int g = gn >> 1, n = gn & 1;
    int cc = w*32 + n*16 + l;
    const float* p = Wh[g] + cc*256 + kt*32 + q*8;
    f32x4 v0 = *(const f32x4*)p;
    f32x4 v1 = *(const f32x4*)(p + 4);
    bf16x8 v;
    v[0]=(__bf16)v0[0]; v[1]=(__bf16)v0[1]; v[2]=(__bf16)v0[2]; v[3]=(__bf16)v0[3];
    v[4]=(__bf16)v1[0]; v[5]=(__bf16)v1[1]; v[6]=(__bf16)v1[2]; v[7]=(__bf16)v1[3];
    if(f == 9)       asm("" : "=a"(aw6o0) : "0"(BC(v)));
    else if(f == 11) asm("" : "=a"(aw6o1) : "0"(BC(v)));
    else             wvf[f] = BC(v);
    if((f & 3) == 3) asm volatile("" ::: "memory");
  }
  /* AGPR frags kt0..4, born class-a at def */
  v4i awf[30];
  #pragma unroll
  for(int f = 0; f < 30; f++){
    int gn = f / 5, kt = f % 5;
    int g = gn >> 1, n = gn & 1;
    int cc = w*32 + n*16 + l;
    const float* p = Wh[g] + cc*256 + kt*32 + q*8;
    f32x4 v0 = *(const f32x4*)p;
    f32x4 v1 = *(const f32x4*)(p + 4);
    bf16x8 v;
    v[0]=(__bf16)v0[0]; v[1]=(__bf16)v0[1]; v[2]=(__bf16)v0[2]; v[3]=(__bf16)v0[3];
    v[4]=(__bf16)v1[0]; v[5]=(__bf16)v1[1]; v[6]=(__bf16)v1[2]; v[7]=(__bf16)v1[3];
    asm("" : "=a"(awf[f]) : "0"(BC(v)));
    if((f % 5) == 4) asm volatile("" ::: "memory");
  }

  f32x4 cst = {0.f, 0.f, 0.f, 0.f};

  /* x prefetch split across waves 6,7 (4 regs each): lanes 0-31, 4 floats each */
  const int wio = (w == 7) ? 4 : 0;
  const int xri = (lane >> 2)*40 + (lane & 3)*8 + wio;
  const float* xbase = x + (size_t)(wgb + (lane >> 2))*4096 + (lane & 3)*8 + wio;
  f32x4 pv = {0.f,0.f,0.f,0.f};
  if(w >= 6 && lane < 32) pv = *(const f32x4*)(xbase + 32);
  asm volatile("" ::: "memory");

  /* persistent weight temps: rotation {kt7f,kt7f,xwf,xwf,kt7g,kt7g} at step entry */
  v4i t0, t1, t2, t3, t4, t5;
  asm volatile(
    "ds_read_b128 %0, %6\n\t"
    "ds_read_b128 %1, %6 offset:1024\n\t"
    "ds_read_b128 %2, %7\n\t"
    "ds_read_b128 %3, %7 offset:1024\n\t"
    "ds_read_b128 %4, %6 offset:16384\n\t"
    "ds_read_b128 %5, %6 offset:17408"
    : "=v"(t0),"=v"(t1),"=v"(t2),"=v"(t3),"=v"(t4),"=v"(t5)
    : "v"(waddr0),"v"(waddr1));

  /* ---------------- recurrence: 128 steps ---------------- */
#define LSTM_STEP(T_, CUR_)                                                     \
  {                                                                             \
    if(w >= 6 && lane < 32){                                                    \
      if((T_) < 127){                                                           \
        bf16x4 v4;                                                              \
        v4[0]=(__bf16)pv[0]; v4[1]=(__bf16)pv[1];                               \
        v4[2]=(__bf16)pv[2]; v4[3]=(__bf16)pv[3];                               \
        *(bf16x4*)&xbuf[(CUR_) ^ 1][xri] = v4;                                  \
      }                                                                         \
      if((T_) < 126) pv = *(const f32x4*)(xbase + ((T_)+2)*32);                 \
    }                                                                           \
    asm volatile("" ::: "memory");                                              \
    v4i A7, Axv;                                                                \
    {                                                                           \
      unsigned hAc = hA0 + (CUR_)*8192u;                                        \
      unsigned xAc = xA0 + (CUR_)*1280u;                                        \
      asm volatile("ds_read_b128 %0, %2 offset:7168\n\t"                        \
                   "ds_read_b128 %1, %3"                                        \
                   : "=v"(A7), "=v"(Axv) : "v"(hAc), "v"(xAc));                 \
    }                                                                           \
    f32x4 z4 = {0.f,0.f,0.f,0.f};                                               \
    v4i acc0 = BC(z4), acc1 = BC(z4), acc2 = BC(z4);                            \
    v4i acc3 = BC(z4), acc4 = BC(z4), acc5 = BC(z4);                            \
    const __bf16* hb = hbuf[CUR_];                                              \
    { v4i a = BC(*(const bf16x8*)&hb[0*512 + l*32 + q*8]); GRP_A("s_nop 3\n\t", a, 0); } \
    { v4i a = BC(*(const bf16x8*)&hb[1*512 + l*32 + q*8]); GRP_A("", a, 1); }   \
    { v4i a = BC(*(const bf16x8*)&hb[2*512 + l*32 + q*8]); GRP_A("", a, 2); }   \
    { v4i a = BC(*(const bf16x8*)&hb[3*512 + l*32 + q*8]); GRP_A("", a, 3); }   \
    { v4i a = BC(*(const bf16x8*)&hb[4*512 + l*32 + q*8]); GRP_A("", a, 4); }   \
    { v4i a = BC(*(const bf16x8*)&hb[5*512 + l*32 + q*8]); GRP_V(a, 0); }       \
    { v4i a = BC(*(const bf16x8*)&hb[6*512 + l*32 + q*8]); GRP_V6(a); }         \
    /* f-tail: kt7+x for gate f; then refill t0-3 with {xwg, kt7o}.         */  \
    /* Pad: MFMA->acc-read needs ~28cyc (hazard recognizer can't see asm;   */  \
    /* bit_cast copies are elided so reads hit acc regs directly).          */  \
    asm volatile(                                                               \
      "s_waitcnt lgkmcnt(0)\n\t"                                                \
      "v_mfma_f32_16x16x32_bf16 %0, %6, %2, %0\n\t"                             \
      "v_mfma_f32_16x16x32_bf16 %1, %6, %3, %1\n\t"                             \
      "s_nop 2\n\t"                                                             \
      "v_mfma_f32_16x16x32_bf16 %0, %7, %4, %0\n\t"                             \
      "v_mfma_f32_16x16x32_bf16 %1, %7, %5, %1\n\t"                             \
      "ds_read_b128 %2, %9 offset:16384\n\t"                                    \
      "ds_read_b128 %3, %9 offset:17408\n\t"                                    \
      "ds_read_b128 %4, %8 offset:32768\n\t"                                    \
      "ds_read_b128 %5, %8 offset:33792\n\t"                                    \
      "s_nop 7\n\t"                                                             \
      "s_nop 7\n\t"                                                             \
      "s_nop 7\n\t"                                                             \
      "s_nop 7"                                                                 \
      : "+v"(acc0),"+v"(acc1),"+v"(t0),"+v"(t1),"+v"(t2),"+v"(t3)               \
      : "v"(A7),"v"(Axv),"v"(waddr0),"v"(waddr1));                              \
    f32x4 vf0 = __builtin_bit_cast(f32x4, acc0);                                \
    f32x4 vf1 = __builtin_bit_cast(f32x4, acc1);                                \
    float fa0=vf0[0], fa1=vf0[1], fa2=vf0[2], fa3=vf0[3];                       \
    float fb0=vf1[0], fb1=vf1[1], fb2=vf1[2], fb3=vf1[3];                       \
    /* g-tail: kt7-g MFMAs, f-gate sigmoid in MFMA shadow, x-g MFMAs, xwo reads */ \
    asm volatile(                                                               \
      "v_mfma_f32_16x16x32_bf16 %0, %14, %10, %0\n\t"                           \
      "v_mfma_f32_16x16x32_bf16 %1, %14, %11, %1\n\t"                           \
      "s_nop 2\n\t"                                                             \
      "v_permlane32_swap_b32 %2, %6\n\t"                                        \
      "v_permlane32_swap_b32 %3, %7\n\t"                                        \
      "v_permlane32_swap_b32 %4, %8\n\t"                                        \
      "v_permlane32_swap_b32 %5, %9\n\t"                                        \
      "v_add_f32 %2, %2, %16\n\t"                                               \
      "v_add_f32 %3, %3, %16\n\t"                                               \
      "v_add_f32 %4, %4, %16\n\t"                                               \
      "v_add_f32 %5, %5, %16\n\t"                                               \
      "v_mul_f32 %2, 0xbfb8aa3b, %2\n\t"                                        \
      "v_mul_f32 %3, 0xbfb8aa3b, %3\n\t"                                        \
      "v_mul_f32 %4, 0xbfb8aa3b, %4\n\t"                                        \
      "v_mul_f32 %5, 0xbfb8aa3b, %5\n\t"                                        \
      "v_exp_f32 %2, %2\n\t"                                                    \
      "v_exp_f32 %3, %3\n\t"                                                    \
      "v_exp_f32 %4, %4\n\t"                                                    \
      "v_exp_f32 %5, %5\n\t"                                                    \
      "v_add_f32 %2, 1.0, %2\n\t"                                               \
      "v_add_f32 %3, 1.0, %3\n\t"                                               \
      "v_add_f32 %4, 1.0, %4\n\t"                                               \
      "v_add_f32 %5, 1.0, %5\n\t"                                               \
      "v_rcp_f32 %2, %2\n\t"                                                    \
      "v_rcp_f32 %3, %3\n\t"                                                    \
      "v_rcp_f32 %4, %4\n\t"                                                    \
      "v_rcp_f32 %5, %5\n\t"                                                    \
      "s_waitcnt lgkmcnt(2)\n\t"                                                \
      "v_mfma_f32_16x16x32_bf16 %0, %15, %12, %0\n\t"                           \
      "v_mfma_f32_16x16x32_bf16 %1, %15, %13, %1\n\t"                           \
      "ds_read_b128 %10, %17 offset:32768\n\t"                                  \
      "ds_read_b128 %11, %17 offset:33792\n\t"                                  \
      "s_nop 7\n\t"                                                             \
      "s_nop 7\n\t"                                                             \
      "s_nop 7\n\t"                                                             \
      "s_nop 7"                                                                 \
      : "+v"(acc2),"+v"(acc3),"+v"(fa0),"+v"(fa1),"+v"(fa2),"+v"(fa3),          \
        "+v"(fb0),"+v"(fb1),"+v"(fb2),"+v"(fb3),"+v"(t4),"+v"(t5)               \
      : "v"(t0),"v"(t1),"v"(A7),"v"(Axv),"v"(b3f),"v"(waddr1));                 \
    f32x4 vg0 = __builtin_bit_cast(f32x4, acc2);                                \
    f32x4 vg1 = __builtin_bit_cast(f32x4, acc3);                                \
    float ga0=vg0[0], ga1=vg0[1], ga2=vg0[2], ga3=vg0[3];                       \
    float gb0=vg1[0], gb1=vg1[1], gb2=vg1[2], gb3=vg1[3];                       \
    /* o-tail: kt7-o MFMAs, g-gate tanh in shadow, x-o MFMAs, next-step prefetch */ \
    asm volatile(                                                               \
      "s_waitcnt lgkmcnt(2)\n\t"                                                \
      "v_mfma_f32_16x16x32_bf16 %0, %16, %12, %0\n\t"                           \
      "v_mfma_f32_16x16x32_bf16 %1, %16, %13, %1\n\t"                           \
      "s_nop 2\n\t"                                                             \
      "v_permlane32_swap_b32 %2, %6\n\t"                                        \
      "v_permlane32_swap_b32 %3, %7\n\t"                                        \
      "v_permlane32_swap_b32 %4, %8\n\t"                                        \
      "v_permlane32_swap_b32 %5, %9\n\t"                                        \
      "v_add_f32 %2, %2, %18\n\t"                                               \
      "v_add_f32 %3, %3, %18\n\t"                                               \
      "v_add_f32 %4, %4, %18\n\t"                                               \
      "v_add_f32 %5, %5, %18\n\t"                                               \
      "v_mul_f32 %2, 0xc038aa3b, %2\n\t"                                        \
      "v_mul_f32 %3, 0xc038aa3b, %3\n\t"                                        \
      "v_mul_f32 %4, 0xc038aa3b, %4\n\t"                                        \
      "v_mul_f32 %5, 0xc038aa3b, %5\n\t"                                        \
      "v_exp_f32 %2, %2\n\t"                                                    \
      "v_exp_f32 %3, %3\n\t"                                                    \
      "v_exp_f32 %4, %4\n\t"                                                    \
      "v_exp_f32 %5, %5\n\t"                                                    \
      "v_add_f32 %2, 1.0, %2\n\t"                                               \
      "v_add_f32 %3, 1.0, %3\n\t"                                               \
      "v_add_f32 %4, 1.0, %4\n\t"                                               \
      "v_add_f32 %5, 1.0, %5\n\t"                                               \
      "v_rcp_f32 %2, %2\n\t"                                                    \
      "v_rcp_f32 %3, %3\n\t"                                                    \
      "v_rcp_f32 %4, %4\n\t"                                                    \
      "v_rcp_f32 %5, %5\n\t"                                                    \
      "v_fma_f32 %2, %2, 2.0, -1.0\n\t"                                         \
      "v_fma_f32 %3, %3, 2.0, -1.0\n\t"                                         \
      "v_fma_f32 %4, %4, 2.0, -1.0\n\t"                                         \
      "v_fma_f32 %5, %5, 2.0, -1.0\n\t"                                         \
      "s_waitcnt lgkmcnt(0)\n\t"                                                \
      "v_mfma_f32_16x16x32_bf16 %0, %17, %14, %0\n\t"                           \
      "v_mfma_f32_16x16x32_bf16 %1, %17, %15, %1\n\t"                           \
      "ds_read_b128 %10, %19\n\t"                                               \
      "ds_read_b128 %11, %19 offset:1024\n\t"                                   \
      "ds_read_b128 %12, %20\n\t"                                               \
      "ds_read_b128 %13, %20 offset:1024\n\t"                                   \
      "ds_read_b128 %14, %19 offset:16384\n\t"                                  \
      "ds_read_b128 %15, %19 offset:17408\n\t"                                  \
      "s_nop 7\n\t"                                                             \
      "s_nop 7\n\t"                                                             \
      "s_nop 7\n\t"                                                             \
      "s_nop 7"                                                                 \
      : "+v"(acc4),"+v"(acc5),"+v"(ga0),"+v"(ga1),"+v"(ga2),"+v"(ga3),          \
        "+v"(gb0),"+v"(gb1),"+v"(gb2),"+v"(gb3),                                \
        "+v"(t0),"+v"(t1),"+v"(t2),"+v"(t3),"+v"(t4),"+v"(t5)                   \
      : "v"(A7),"v"(Axv),"v"(b3g),"v"(waddr0),"v"(waddr1));                     \
    f32x4 vo0 = __builtin_bit_cast(f32x4, acc4);                                \
    f32x4 vo1 = __builtin_bit_cast(f32x4, acc5);                                \
    float oa0=vo0[0], oa1=vo0[1], oa2=vo0[2], oa3=vo0[3];                       \
    float ob0=vo1[0], ob1=vo1[1], ob2=vo1[2], ob3=vo1[3];                       \
    asm volatile(                                                               \
      "s_nop 1\n\t"                                                             \
      "v_permlane32_swap_b32 %0, %4\n\t"                                        \
      "v_permlane32_swap_b32 %1, %5\n\t"                                        \
      "v_permlane32_swap_b32 %2, %6\n\t"                                        \
      "v_permlane32_swap_b32 %3, %7"                                            \
      : "+v"(oa0),"+v"(oa1),"+v"(oa2),"+v"(oa3),                                \
        "+v"(ob0),"+v"(ob1),"+v"(ob2),"+v"(ob3));                               \
    __bf16* hbw = &hbuf[(CUR_) ^ 1][hwb];                                       \
    { float ov = sigm(oa0 + b3o); float cc = fa0*cst[0] + igv[0]*ga0;           \
      cst[0] = cc; hbw[0]  = (__bf16)(ov * ftanh(cc)); }                        \
    { float ov = sigm(oa1 + b3o); float cc = fa1*cst[1] + igv[1]*ga1;           \
      cst[1] = cc; hbw[32] = (__bf16)(ov * ftanh(cc)); }                        \
    { float ov = sigm(oa2 + b3o); float cc = fa2*cst[2] + igv[2]*ga2;           \
      cst[2] = cc; hbw[64] = (__bf16)(ov * ftanh(cc)); }                        \
    { float ov = sigm(oa3 + b3o); float cc = fa3*cst[3] + igv[3]*ga3;           \
      cst[3] = cc; hbw[96] = (__bf16)(ov * ftanh(cc)); }                        \
    BARRIER();                                                                  \
  }

  #pragma unroll 1
  for(int tt = 0; tt < 64; tt++){
    LSTM_STEP(2*tt,     0)
    LSTM_STEP(2*tt + 1, 1)
  }
#undef LSTM_STEP

  /* ---------------- head ---------------- */
  f32x4 hd[2];
  { f32x4 z4 = {0.f,0.f,0.f,0.f}; hd[0] = z4; hd[1] = z4; }
  #pragma unroll 2
  for(int kt=0; kt<8; kt++){
    bf16x8 a = *(const bf16x8*)&hbuf[0][kt*512 + l*32 + q*8];
    #pragma unroll
    for(int n=0;n<2;n++){
      int cc = w*32 + n*16 + l;
      const float* p = Wd0 + cc*268 + kt*32 + q*8;
      bf16x8 b;
      #pragma unroll
      for(int j=0;j<8;j++) b[j] = (__bf16)p[j];
      hd[n] = MFMA(a, b, hd[n]);
    }
  }
  {
    bf16x8 a;
    #pragma unroll
    for(int j=0;j<8;j++){
      int k2 = q*8 + j;
      a[j] = (__bf16)((l < 8 && k2 < 12) ? pm[(size_t)(wgb + l)*12 + k2] : 0.0f);
    }
    #pragma unroll
    for(int n=0;n<2;n++){
      int cc = w*32 + n*16 + l;
      bf16x8 b;
      #pragma unroll
      for(int j=0;j<8;j++){
        int k2 = q*8 + j;
        b[j] = (__bf16)((k2 < 12) ? Wd0[cc*268 + 256 + k2] : 0.0f);
      }
      hd[n] = MFMA(a, b, hd[n]);
    }
  }
  float* z1 = (float*)wlds;
  #pragma unroll
  for(int n=0;n<2;n++){
    int cc = w*32 + n*16 + l;
    float bb = bd0[cc];
    #pragma unroll
    for(int i=0;i<4;i++) z1[(q*4 + i)*264 + cc] = hd[n][i] + bb;
  }
  __syncthreads();
  if(tid < 256){
    int row = tid >> 5, seg = tid & 31;
    const float* zr = &z1[row*264 + seg*8];
    const float* wr = Wd1 + seg*8;
    float s = 0.0f;
    #pragma unroll
    for(int j=0;j<8;j++) s += zr[j] * wr[j];
    s += __shfl_xor(s, 1);
    s += __shfl_xor(s, 2);
    s += __shfl_xor(s, 4);
    s += __shfl_xor(s, 8);
    s += __shfl_xor(s, 16);
    if(seg == 0) out[wgb + row] = s + bd1[0];
  }
}

extern "C" void kernel_launch(void* const* d_in, const int* in_sizes, int n_in,
                              void* d_out, int out_size, void* d_ws, size_t ws_size,
                              hipStream_t stream) {
  const float* x       = (const float*)d_in[0];
  const float* latlons = (const float*)d_in[1];
  const float* yearly  = (const float*)d_in[2];
  const float* pm      = (const float*)d_in[3];
  const float* Wf_i    = (const float*)d_in[4];
  const float* Wf_h    = (const float*)d_in[5];
  const float* bf_h    = (const float*)d_in[6];
  const float* Wu      = (const float*)d_in[7];
  const float* bu      = (const float*)d_in[8];
  const float* Wg_i    = (const float*)d_in[9];
  const float* Wg_h    = (const float*)d_in[10];
  const float* bg_h    = (const float*)d_in[11];
  const float* Wo_i    = (const float*)d_in[12];
  const float* Wo_h    = (const float*)d_in[13];
  const float* bo_h    = (const float*)d_in[14];
  const float* Wd0     = (const float*)d_in[15];
  const float* bd0     = (const float*)d_in[16];
  const float* Wd1     = (const float*)d_in[17];
  const float* bd1     = (const float*)d_in[18];

  ealstm_kernel<<<dim3(256), dim3(512), 0, stream>>>(
      x, latlons, yearly, pm,
      Wf_i, Wf_h, bf_h, Wu, bu,
      Wg_i, Wg_h, bg_h, Wo_i, Wo_h, bo_h,
      Wd0, bd0, Wd1, bd1,
      (float*)d_out);
}

// Round 3
// 343.819 us; speedup vs baseline: 1.1589x; 1.1589x over previous
//
#include <hip/hip_runtime.h>

typedef __bf16 bf16x8 __attribute__((ext_vector_type(8)));
typedef float  f32x4  __attribute__((ext_vector_type(4)));
typedef int    v4i    __attribute__((ext_vector_type(4)));

#define LOG2E 1.4426950408889634f

__device__ __forceinline__ float fexp(float x){ return __builtin_amdgcn_exp2f(x * LOG2E); }
__device__ __forceinline__ float sigm(float x){ return __builtin_amdgcn_rcpf(1.0f + fexp(-x)); }
// tanh(x) = 2*sigm(2x)-1 ; exp2 over/underflow saturate correctly
__device__ __forceinline__ float ftanh(float x){
  float r = __builtin_amdgcn_rcpf(1.0f + __builtin_amdgcn_exp2f(-2.0f*LOG2E*x));
  return 2.0f*r - 1.0f;
}
__device__ __forceinline__ f32x4 MFMA(bf16x8 a, bf16x8 b, f32x4 c){
  return __builtin_amdgcn_mfma_f32_16x16x32_bf16(a, b, c, 0, 0, 0);
}
#define BC(w) __builtin_bit_cast(v4i, (w))

// Budget discipline: <=128 of EACH register class.
//   AGPR: 30 weight frags (K-tiles 0..4) = 120, born class-a via "=a" tie at def.
//   arch: 12 weight frags (K-tiles 5..6) = 48 + accs 24 + loop state ~50.
#define GRP_A(LEAD, A_, KT_) asm volatile(LEAD                  \
    "v_mfma_f32_16x16x32_bf16 %0, %6, %7, %0\n\t"               \
    "v_mfma_f32_16x16x32_bf16 %1, %6, %8, %1\n\t"               \
    "v_mfma_f32_16x16x32_bf16 %2, %6, %9, %2\n\t"               \
    "v_mfma_f32_16x16x32_bf16 %3, %6, %10, %3\n\t"              \
    "v_mfma_f32_16x16x32_bf16 %4, %6, %11, %4\n\t"              \
    "v_mfma_f32_16x16x32_bf16 %5, %6, %12, %5\n\t"              \
    "s_nop 3"                                                   \
    : "+v"(acc0),"+v"(acc1),"+v"(acc2),"+v"(acc3),"+v"(acc4),"+v"(acc5) \
    : "v"(A_), "a"(awf[(KT_)]),"a"(awf[(KT_)+5]),"a"(awf[(KT_)+10]),    \
      "a"(awf[(KT_)+15]),"a"(awf[(KT_)+20]),"a"(awf[(KT_)+25]))

#define GRP_V(A_, O_) asm volatile(                             \
    "v_mfma_f32_16x16x32_bf16 %0, %6, %7, %0\n\t"               \
    "v_mfma_f32_16x16x32_bf16 %1, %6, %8, %1\n\t"               \
    "v_mfma_f32_16x16x32_bf16 %2, %6, %9, %2\n\t"               \
    "v_mfma_f32_16x16x32_bf16 %3, %6, %10, %3\n\t"              \
    "v_mfma_f32_16x16x32_bf16 %4, %6, %11, %4\n\t"              \
    "v_mfma_f32_16x16x32_bf16 %5, %6, %12, %5\n\t"              \
    "s_nop 3"                                                   \
    : "+v"(acc0),"+v"(acc1),"+v"(acc2),"+v"(acc3),"+v"(acc4),"+v"(acc5) \
    : "v"(A_), "v"(wvf[(O_)]),"v"(wvf[(O_)+2]),"v"(wvf[(O_)+4]),        \
      "v"(wvf[(O_)+6]),"v"(wvf[(O_)+8]),"v"(wvf[(O_)+10]))

// h K-tile 7 + x K-tile in ONE asm: 12 ds_reads, only 2 lgkm waits exposed.
#define GRP_LX(A7_, AX_) asm volatile(                          \
    "ds_read_b128 %6, %14\n\t"                                  \
    "ds_read_b128 %7, %14 offset:1024\n\t"                      \
    "ds_read_b128 %8, %14 offset:16384\n\t"                     \
    "ds_read_b128 %9, %14 offset:17408\n\t"                     \
    "ds_read_b128 %10, %14 offset:32768\n\t"                    \
    "ds_read_b128 %11, %14 offset:33792\n\t"                    \
    "s_waitcnt lgkmcnt(0)\n\t"                                  \
    "v_mfma_f32_16x16x32_bf16 %0, %12, %6, %0\n\t"              \
    "v_mfma_f32_16x16x32_bf16 %1, %12, %7, %1\n\t"              \
    "v_mfma_f32_16x16x32_bf16 %2, %12, %8, %2\n\t"              \
    "v_mfma_f32_16x16x32_bf16 %3, %12, %9, %3\n\t"              \
    "v_mfma_f32_16x16x32_bf16 %4, %12, %10, %4\n\t"             \
    "v_mfma_f32_16x16x32_bf16 %5, %12, %11, %5\n\t"             \
    "ds_read_b128 %6, %15\n\t"                                  \
    "ds_read_b128 %7, %15 offset:1024\n\t"                      \
    "ds_read_b128 %8, %15 offset:16384\n\t"                     \
    "ds_read_b128 %9, %15 offset:17408\n\t"                     \
    "ds_read_b128 %10, %15 offset:32768\n\t"                    \
    "ds_read_b128 %11, %15 offset:33792\n\t"                    \
    "s_waitcnt lgkmcnt(0)\n\t"                                  \
    "v_mfma_f32_16x16x32_bf16 %0, %13, %6, %0\n\t"              \
    "v_mfma_f32_16x16x32_bf16 %1, %13, %7, %1\n\t"              \
    "v_mfma_f32_16x16x32_bf16 %2, %13, %8, %2\n\t"              \
    "v_mfma_f32_16x16x32_bf16 %3, %13, %9, %3\n\t"              \
    "v_mfma_f32_16x16x32_bf16 %4, %13, %10, %4\n\t"             \
    "v_mfma_f32_16x16x32_bf16 %5, %13, %11, %5\n\t"             \
    "s_nop 3"                                                   \
    : "+v"(acc0),"+v"(acc1),"+v"(acc2),"+v"(acc3),"+v"(acc4),"+v"(acc5), \
      "=&v"(t0),"=&v"(t1),"=&v"(t2),"=&v"(t3),"=&v"(t4),"=&v"(t5)        \
    : "v"(A7_), "v"(AX_), "v"(waddr0), "v"(waddr1))

// Raw workgroup barrier: drain LDS but NOT vmcnt (x prefetch stays in flight).
#define BARRIER() asm volatile("s_waitcnt lgkmcnt(0)\n\ts_barrier" ::: "memory")

// B=2048, T=128, D=32, H=256, S=39, PM=12
// 256 wg x 512 threads (8 waves), 8 batch rows per wg (tile rows 8-15 zero).
__global__ void
__attribute__((amdgpu_flat_work_group_size(512,512), amdgpu_waves_per_eu(2,2)))
ealstm_kernel(
    const float* __restrict__ x,      const float* __restrict__ latlons,
    const float* __restrict__ yearly, const float* __restrict__ pm,
    const float* __restrict__ Wf_i, const float* __restrict__ Wf_h, const float* __restrict__ bf_h,
    const float* __restrict__ Wu,   const float* __restrict__ bu,
    const float* __restrict__ Wg_i, const float* __restrict__ Wg_h, const float* __restrict__ bg_h,
    const float* __restrict__ Wo_i, const float* __restrict__ Wo_h, const float* __restrict__ bo_h,
    const float* __restrict__ Wd0,  const float* __restrict__ bd0,
    const float* __restrict__ Wd1,  const float* __restrict__ bd1,
    float* __restrict__ out)
{
  // LDS: 16384 + 2560 + 98304 + 4096 = 121344 B (1 block/CU)
  __shared__ __align__(16) __bf16 hbuf[2][4096];
  __shared__ __align__(16) __bf16 xbuf[2][16*40];
  __shared__ __align__(16) __bf16 wlds[2*48*512];
  __shared__ __align__(16) float  xs[16*64];

  const int tid  = threadIdx.x;
  const int w    = tid >> 6;
  const int lane = tid & 63;
  const int q    = lane >> 4;
  const int l    = lane & 15;
  const int wgb  = blockIdx.x * 8;

  const float* Wh[3] = {Wf_h, Wg_h, Wo_h};
  const float* Wi[3] = {Wf_i, Wg_i, Wo_i};

  // ---------------- init: LDS fills ----------------
  for(int idx = tid; idx < 16*64; idx += 512){
    int m = idx >> 6, k = idx & 63;
    float v = 0.0f;
    if(m < 8){
      int b = wgb + m;
      if(k < 2) v = latlons[b*2 + k];
      else if(k < 39) v = yearly[b*37 + (k-2)];
    }
    xs[idx] = v;
  }
  for(int idx = tid; idx < 2*4096; idx += 512) ((__bf16*)hbuf)[idx] = (__bf16)0.0f;
  { // xbuf rows 8-15 of both buffers: zero
    int buf = tid >> 8, r = 8 + ((tid >> 5) & 7), c = tid & 31;
    xbuf[buf][r*40 + c] = (__bf16)0.0f;
  }
  if(tid < 256){ // t=0, rows 0-7
    int m = tid >> 5, k = tid & 31;
    xbuf[0][m*40 + k] = (__bf16)x[(size_t)(wgb + m)*4096 + k];
  }
  for(int grp = tid; grp < 2*48*64; grp += 512){
    int frag = grp >> 6, ln = grp & 63;
    int kk = frag / 48, f2 = frag % 48;
    int g = f2 >> 4, nt = f2 & 15;
    int q2 = ln >> 4, l2 = ln & 15;
    int cc = nt*16 + l2;
    const float* p = (kk == 0) ? (Wh[g] + cc*256 + 224 + q2*8)
                               : (Wi[g] + cc*32  + q2*8);
    bf16x8 v;
    #pragma unroll
    for(int j=0;j<8;j++) v[j] = (__bf16)p[j];
    *(bf16x8*)&wlds[frag*512 + ln*8] = v;
  }

  const int  srcl = lane & 31;
  const bool lo   = lane < 32;
  const int  qq4  = (q & 1) * 4;
  const int  colw = w*32 + ((lane & 32) >> 1) + l;
  const int  hwb  = (colw >> 5)*512 + qq4*32 + ((colw >> 3) & 3)*8 + (colw & 7);
  const unsigned waddr0 = (unsigned)(unsigned long long)&wlds[(0*48 + w*2)*512 + lane*8];
  const unsigned waddr1 = waddr0 + 49152u;
  const float b3f = bf_h[colw], b3g = bg_h[colw], b3o = bo_h[colw];

  __syncthreads();

  // ---------------- i_gate = sigmoid(x_s @ Wu^T + bu), redistributed ----------------
  f32x4 igv;
  {
    float bu0 = bu[w*32 + l], bu1 = bu[w*32 + 16 + l];
    f32x4 iga0 = {bu0,bu0,bu0,bu0};
    f32x4 iga1 = {bu1,bu1,bu1,bu1};
    #pragma unroll
    for(int kt=0; kt<2; kt++){
      bf16x8 a;
      const float* xr = &xs[l*64 + kt*32 + q*8];
      #pragma unroll
      for(int j=0;j<8;j++) a[j] = (__bf16)xr[j];
      #pragma unroll
      for(int n=0;n<2;n++){
        int cc = w*32 + n*16 + l;
        bf16x8 b;
        #pragma unroll
        for(int j=0;j<8;j++){
          int k = kt*32 + q*8 + j;
          b[j] = (__bf16)((k < 39) ? Wu[cc*39 + k] : 0.0f);
        }
        if(n == 0) iga0 = MFMA(a, b, iga0); else iga1 = MFMA(a, b, iga1);
      }
    }
    #pragma unroll
    for(int i=0;i<4;i++){
      float s0 = sigm(iga0[i]);
      float s1 = __shfl(sigm(iga1[i]), srcl);
      igv[i] = lo ? s0 : s1;
    }
  }

  // ---------------- weight frags LAST (minimal live-across pressure) ----------
  v4i wvf[12];
  #pragma unroll
  for(int f = 0; f < 12; f++){
    int gn = f >> 1, kt = 5 + (f & 1);
    int g = gn >> 1, n = gn & 1;
    int cc = w*32 + n*16 + l;
    const float* p = Wh[g] + cc*256 + kt*32 + q*8;
    f32x4 v0 = *(const f32x4*)p;
    f32x4 v1 = *(const f32x4*)(p + 4);
    bf16x8 v;
    v[0]=(__bf16)v0[0]; v[1]=(__bf16)v0[1]; v[2]=(__bf16)v0[2]; v[3]=(__bf16)v0[3];
    v[4]=(__bf16)v1[0]; v[5]=(__bf16)v1[1]; v[6]=(__bf16)v1[2]; v[7]=(__bf16)v1[3];
    wvf[f] = BC(v);
    if((f & 3) == 3) asm volatile("" ::: "memory");  // choke load batching
  }
  v4i awf[30];
  #pragma unroll
  for(int f = 0; f < 30; f++){
    int gn = f / 5, kt = f % 5;
    int g = gn >> 1, n = gn & 1;
    int cc = w*32 + n*16 + l;
    const float* p = Wh[g] + cc*256 + kt*32 + q*8;
    f32x4 v0 = *(const f32x4*)p;
    f32x4 v1 = *(const f32x4*)(p + 4);
    bf16x8 v;
    v[0]=(__bf16)v0[0]; v[1]=(__bf16)v0[1]; v[2]=(__bf16)v0[2]; v[3]=(__bf16)v0[3];
    v[4]=(__bf16)v1[0]; v[5]=(__bf16)v1[1]; v[6]=(__bf16)v1[2]; v[7]=(__bf16)v1[3];
    asm("" : "=a"(awf[f]) : "0"(BC(v)));
    if((f % 5) == 4) asm volatile("" ::: "memory");  // choke load batching
  }

  f32x4 cst = {0.f, 0.f, 0.f, 0.f};

  // x prefetch state (wave 7, lanes 0-31): pv holds x_{t+1} at step t entry.
  const int xri = (lane >> 2)*40 + (lane & 3)*8;   // xbuf store index
  const float* xbase = x + (size_t)(wgb + (lane >> 2))*4096 + (lane & 3)*8;
  f32x4 pv0 = {0.f,0.f,0.f,0.f}, pv1 = {0.f,0.f,0.f,0.f};
  if(w == 7 && lane < 32){
    pv0 = *(const f32x4*)(xbase + 32);
    pv1 = *(const f32x4*)(xbase + 36);
  }
  asm volatile("" ::: "memory");

  // ---------------- recurrence: 128 steps, 1 raw barrier/step ----------------
#define LSTM_STEP(T_, CUR_)                                                     \
  {                                                                             \
    if(w == 7 && lane < 32){                                                    \
      if((T_) < 127){                                                           \
        bf16x8 v;                                                               \
        v[0]=(__bf16)pv0[0]; v[1]=(__bf16)pv0[1]; v[2]=(__bf16)pv0[2]; v[3]=(__bf16)pv0[3]; \
        v[4]=(__bf16)pv1[0]; v[5]=(__bf16)pv1[1]; v[6]=(__bf16)pv1[2]; v[7]=(__bf16)pv1[3]; \
        *(bf16x8*)&xbuf[(CUR_) ^ 1][xri] = v;                                   \
      }                                                                         \
      if((T_) < 126){                                                           \
        pv0 = *(const f32x4*)(xbase + ((T_)+2)*32);                             \
        pv1 = *(const f32x4*)(xbase + ((T_)+2)*32 + 4);                         \
      }                                                                         \
    }                                                                           \
    asm volatile("" ::: "memory");                                              \
    f32x4 z4 = {0.f,0.f,0.f,0.f};                                               \
    v4i acc0 = BC(z4), acc1 = BC(z4), acc2 = BC(z4);                            \
    v4i acc3 = BC(z4), acc4 = BC(z4), acc5 = BC(z4);                            \
    v4i t0, t1, t2, t3, t4, t5;                                                 \
    const __bf16* hb = hbuf[CUR_];                                              \
    { v4i a = BC(*(const bf16x8*)&hb[0*512 + l*32 + q*8]); GRP_A("s_nop 3\n\t", a, 0); } \
    { v4i a = BC(*(const bf16x8*)&hb[1*512 + l*32 + q*8]); GRP_A("", a, 1); }   \
    { v4i a = BC(*(const bf16x8*)&hb[2*512 + l*32 + q*8]); GRP_A("", a, 2); }   \
    { v4i a = BC(*(const bf16x8*)&hb[3*512 + l*32 + q*8]); GRP_A("", a, 3); }   \
    { v4i a = BC(*(const bf16x8*)&hb[4*512 + l*32 + q*8]); GRP_A("", a, 4); }   \
    { v4i a = BC(*(const bf16x8*)&hb[5*512 + l*32 + q*8]); GRP_V(a, 0); }       \
    { v4i a = BC(*(const bf16x8*)&hb[6*512 + l*32 + q*8]); GRP_V(a, 1); }       \
    { v4i a7 = BC(*(const bf16x8*)&hb[7*512 + l*32 + q*8]);                     \
      v4i ax = BC(*(const bf16x8*)&xbuf[CUR_][l*40 + q*8]);                     \
      GRP_LX(a7, ax); }                                                         \
    asm volatile("s_nop 7\n\ts_nop 7\n\ts_nop 7"                                \
      : "+v"(acc0),"+v"(acc1),"+v"(acc2),"+v"(acc3),"+v"(acc4),"+v"(acc5));     \
    f32x4 a0 = __builtin_bit_cast(f32x4, acc0);                                 \
    f32x4 a1 = __builtin_bit_cast(f32x4, acc1);                                 \
    f32x4 a2 = __builtin_bit_cast(f32x4, acc2);                                 \
    f32x4 a3 = __builtin_bit_cast(f32x4, acc3);                                 \
    f32x4 a4 = __builtin_bit_cast(f32x4, acc4);                                 \
    f32x4 a5 = __builtin_bit_cast(f32x4, acc5);                                 \
    float f0=a0[0], f1=a0[1], f2=a0[2], f3=a0[3];                               \
    float F0=a1[0], F1=a1[1], F2=a1[2], F3=a1[3];                               \
    float g0=a2[0], g1=a2[1], g2=a2[2], g3=a2[3];                               \
    float G0=a3[0], G1=a3[1], G2=a3[2], G3=a3[3];                               \
    float o0=a4[0], o1=a4[1], o2=a4[2], o3=a4[3];                               \
    float O0=a5[0], O1=a5[1], O2=a5[2], O3=a5[3];                               \
    /* hi-lanes take the n=1 half: dst.hi <- src.lo == (lo ? a0 : shfl(a1)) */  \
    asm volatile(                                                               \
      "s_nop 3\n\t"                                                             \
      "v_permlane32_swap_b32 %0, %12\n\t"                                       \
      "v_permlane32_swap_b32 %1, %13\n\t"                                       \
      "v_permlane32_swap_b32 %2, %14\n\t"                                       \
      "v_permlane32_swap_b32 %3, %15\n\t"                                       \
      "v_permlane32_swap_b32 %4, %16\n\t"                                       \
      "v_permlane32_swap_b32 %5, %17\n\t"                                       \
      "v_permlane32_swap_b32 %6, %18\n\t"                                       \
      "v_permlane32_swap_b32 %7, %19\n\t"                                       \
      "v_permlane32_swap_b32 %8, %20\n\t"                                       \
      "v_permlane32_swap_b32 %9, %21\n\t"                                       \
      "v_permlane32_swap_b32 %10, %22\n\t"                                      \
      "v_permlane32_swap_b32 %11, %23"                                          \
      : "+v"(f0),"+v"(f1),"+v"(f2),"+v"(f3),                                    \
        "+v"(g0),"+v"(g1),"+v"(g2),"+v"(g3),                                    \
        "+v"(o0),"+v"(o1),"+v"(o2),"+v"(o3),                                    \
        "+v"(F0),"+v"(F1),"+v"(F2),"+v"(F3),                                    \
        "+v"(G0),"+v"(G1),"+v"(G2),"+v"(G3),                                    \
        "+v"(O0),"+v"(O1),"+v"(O2),"+v"(O3));                                   \
    __bf16* hbw = &hbuf[(CUR_) ^ 1][hwb];                                       \
    { float fv=sigm(f0+b3f), gv=ftanh(g0+b3g), ov=sigm(o0+b3o);                 \
      float cc=fv*cst[0]+igv[0]*gv; cst[0]=cc; hbw[0]  = (__bf16)(ov*ftanh(cc)); } \
    { float fv=sigm(f1+b3f), gv=ftanh(g1+b3g), ov=sigm(o1+b3o);                 \
      float cc=fv*cst[1]+igv[1]*gv; cst[1]=cc; hbw[32] = (__bf16)(ov*ftanh(cc)); } \
    { float fv=sigm(f2+b3f), gv=ftanh(g2+b3g), ov=sigm(o2+b3o);                 \
      float cc=fv*cst[2]+igv[2]*gv; cst[2]=cc; hbw[64] = (__bf16)(ov*ftanh(cc)); } \
    { float fv=sigm(f3+b3f), gv=ftanh(g3+b3g), ov=sigm(o3+b3o);                 \
      float cc=fv*cst[3]+igv[3]*gv; cst[3]=cc; hbw[96] = (__bf16)(ov*ftanh(cc)); } \
    BARRIER();                                                                  \
  }

  #pragma unroll 1
  for(int tt = 0; tt < 64; tt++){
    LSTM_STEP(2*tt,     0)
    LSTM_STEP(2*tt + 1, 1)
  }
#undef LSTM_STEP

  // ---------------- head: z1 = [h_last, pm] @ Wd0^T + bd0 ; out = z1 @ Wd1^T + bd1 ----------------
  f32x4 hd[2];
  { f32x4 z4 = {0.f,0.f,0.f,0.f}; hd[0] = z4; hd[1] = z4; }
  #pragma unroll 2
  for(int kt=0; kt<8; kt++){
    bf16x8 a = *(const bf16x8*)&hbuf[0][kt*512 + l*32 + q*8];
    #pragma unroll
    for(int n=0;n<2;n++){
      int cc = w*32 + n*16 + l;
      const float* p = Wd0 + cc*268 + kt*32 + q*8;
      bf16x8 b;
      #pragma unroll
      for(int j=0;j<8;j++) b[j] = (__bf16)p[j];
      hd[n] = MFMA(a, b, hd[n]);
    }
  }
  { // K-tile 8: pm (k=256..267); only rows l<8 are real
    bf16x8 a;
    #pragma unroll
    for(int j=0;j<8;j++){
      int k2 = q*8 + j;
      a[j] = (__bf16)((l < 8 && k2 < 12) ? pm[(size_t)(wgb + l)*12 + k2] : 0.0f);
    }
    #pragma unroll
    for(int n=0;n<2;n++){
      int cc = w*32 + n*16 + l;
      bf16x8 b;
      #pragma unroll
      for(int j=0;j<8;j++){
        int k2 = q*8 + j;
        b[j] = (__bf16)((k2 < 12) ? Wd0[cc*268 + 256 + k2] : 0.0f);
      }
      hd[n] = MFMA(a, b, hd[n]);
    }
  }
  float* z1 = (float*)wlds;   // wlds reads all precede the loop-final barrier
  #pragma unroll
  for(int n=0;n<2;n++){
    int cc = w*32 + n*16 + l;
    float bb = bd0[cc];
    #pragma unroll
    for(int i=0;i<4;i++) z1[(q*4 + i)*264 + cc] = hd[n][i] + bb;
  }
  __syncthreads();
  if(tid < 256){
    int row = tid >> 5, seg = tid & 31;   // rows 0-7 x 32 segments
    const float* zr = &z1[row*264 + seg*8];
    const float* wr = Wd1 + seg*8;
    float s = 0.0f;
    #pragma unroll
    for(int j=0;j<8;j++) s += zr[j] * wr[j];
    s += __shfl_xor(s, 1);
    s += __shfl_xor(s, 2);
    s += __shfl_xor(s, 4);
    s += __shfl_xor(s, 8);
    s += __shfl_xor(s, 16);
    if(seg == 0) out[wgb + row] = s + bd1[0];
  }
}

extern "C" void kernel_launch(void* const* d_in, const int* in_sizes, int n_in,
                              void* d_out, int out_size, void* d_ws, size_t ws_size,
                              hipStream_t stream) {
  const float* x       = (const float*)d_in[0];
  const float* latlons = (const float*)d_in[1];
  const float* yearly  = (const float*)d_in[2];
  const float* pm      = (const float*)d_in[3];
  const float* Wf_i    = (const float*)d_in[4];
  const float* Wf_h    = (const float*)d_in[5];
  const float* bf_h    = (const float*)d_in[6];
  const float* Wu      = (const float*)d_in[7];
  const float* bu      = (const float*)d_in[8];
  const float* Wg_i    = (const float*)d_in[9];
  const float* Wg_h    = (const float*)d_in[10];
  const float* bg_h    = (const float*)d_in[11];
  const float* Wo_i    = (const float*)d_in[12];
  const float* Wo_h    = (const float*)d_in[13];
  const float* bo_h    = (const float*)d_in[14];
  const float* Wd0     = (const float*)d_in[15];
  const float* bd0     = (const float*)d_in[16];
  const float* Wd1     = (const float*)d_in[17];
  const float* bd1     = (const float*)d_in[18];

  ealstm_kernel<<<dim3(256), dim3(512), 0, stream>>>(
      x, latlons, yearly, pm,
      Wf_i, Wf_h, bf_h, Wu, bu,
      Wg_i, Wg_h, bg_h, Wo_i, Wo_h, bo_h,
      Wd0, bd0, Wd1, bd1,
      (float*)d_out);
}